// Round 7
// baseline (998.596 us; speedup 1.0000x reference)
//
#include <hip/hip_runtime.h>
#include <hip/hip_bf16.h>

// Problem constants (from reference)
#define N_NODES 50000
#define E_EDGES 1600000
#define FIN 512
#define FOUT 256
#define NCOMB 768      // 3 * FOUT, fused GEMM N
#define TAO_F 3.0f
#define M_PAD 50048    // 391 * 128
#define NB 391         // buckets of 128 rows, bucket = row >> 7
#define CSTRIDE 16     // global counter padding (one per 64B line)
#define CH 4096        // edges per block in pass 1
#define CSH 11         // col-chunk shift: col>>11 -> 25 chunks of 2048 cols (1 MB of H)
#define NCH 25
#define NGRP 3128      // NB*8 groups of 16 rows; group = row>>4

#define GEMM_WGS 2346  // 391 * 6 workgroups, flattened
#define GEMM_Q  (GEMM_WGS / 8)   // 293
#define GEMM_R  (GEMM_WGS % 8)   // 2

typedef __bf16 bf16x8 __attribute__((ext_vector_type(8)));
typedef float  f32x4  __attribute__((ext_vector_type(4)));

static __device__ __forceinline__ unsigned short f2bf(float f) {
    unsigned int u = __float_as_uint(f);
    u += 0x7FFFu + ((u >> 16) & 1u);   // round-to-nearest-even
    return (unsigned short)(u >> 16);
}
static __device__ __forceinline__ float bf2f(unsigned short h) {
    return __uint_as_float(((unsigned int)h) << 16);
}

// ---------------- conversion kernels ----------------
__global__ void convert_x_kernel(const float* __restrict__ X, unsigned short* __restrict__ Xb) {
    long long i = ((long long)blockIdx.x * blockDim.x + threadIdx.x) * 4;
    const long long total = (long long)M_PAD * FIN;
    if (i >= total) return;
    const long long valid = (long long)N_NODES * FIN;   // divisible by 4
    ushort4 o;
    if (i < valid) {
        const float4 v = *reinterpret_cast<const float4*>(X + i);
        o.x = f2bf(v.x); o.y = f2bf(v.y); o.z = f2bf(v.z); o.w = f2bf(v.w);
    } else {
        o.x = o.y = o.z = o.w = 0;
    }
    *reinterpret_cast<ushort4*>(Xb + i) = o;
}

// three W (FIN x FOUT f32) -> combined Wt (NCOMB x FIN bf16), row w*256+n = col n of W_w
__global__ void convert_w_kernel(const float* __restrict__ Wm, const float* __restrict__ Wa,
                                 const float* __restrict__ Was, unsigned short* __restrict__ Wt) {
    int i = blockIdx.x * blockDim.x + threadIdx.x;
    if (i >= NCOMB * FIN) return;
    int row = i / FIN, k = i % FIN;
    int w = row >> 8, n = row & 255;
    const float* W = (w == 0) ? Wm : (w == 1) ? Wa : Was;
    Wt[i] = f2bf(W[(size_t)k * FOUT + n]);
}

// ---------------- fused bf16 MFMA GEMM: [out|H_A|H_As] = A(M_PAD x FIN) * Wt(NCOMB x FIN)^T ----
// 1D grid, XCD-chunked swizzle (bijective)
#define BM 128
#define BN 128
#define BK 64

__global__ __launch_bounds__(256) void gemm_kernel(const unsigned short* __restrict__ A,
                                                   const unsigned short* __restrict__ Bt,
                                                   float* __restrict__ Omlp,
                                                   unsigned short* __restrict__ HA,
                                                   unsigned short* __restrict__ HAs) {
    __shared__ unsigned short As[BM * BK];   // [128][64] linear (global_load_lds dest)
    __shared__ unsigned short Bs[BN * BK];
    const int b = blockIdx.x;
    const int xcd = b & 7, ii = b >> 3;
    const int work = (xcd < GEMM_R ? xcd * (GEMM_Q + 1)
                                   : GEMM_R * (GEMM_Q + 1) + (xcd - GEMM_R) * GEMM_Q) + ii;
    const int py = work / 6, px = work - py * 6;
    const int row0 = py * BM, col0 = px * BN;
    const int tid = threadIdx.x;
    const int lane = tid & 63, wave = tid >> 6;
    const int wr = wave >> 1, wc = wave & 1;          // 2x2 waves -> 64x64 each
    const int st_row = tid >> 3;
    const int st_col = (tid & 7) * 8;
    const int lds_off = wave * 512;
    const unsigned short* Ag = A + (size_t)(row0 + st_row) * FIN + st_col;
    const unsigned short* Bg = Bt + (size_t)(col0 + st_row) * FIN + st_col;
    f32x4 acc[4][4] = {};

    for (int k0 = 0; k0 < FIN; k0 += BK) {
#pragma unroll
        for (int i = 0; i < 4; i++) {
            __builtin_amdgcn_global_load_lds(
                (const __attribute__((address_space(1))) unsigned int*)(Ag + (size_t)i * 32 * FIN + k0),
                (__attribute__((address_space(3))) unsigned int*)&As[i * 2048 + lds_off], 16, 0, 0);
            __builtin_amdgcn_global_load_lds(
                (const __attribute__((address_space(1))) unsigned int*)(Bg + (size_t)i * 32 * FIN + k0),
                (__attribute__((address_space(3))) unsigned int*)&Bs[i * 2048 + lds_off], 16, 0, 0);
        }
        __syncthreads();
#pragma unroll
        for (int kk = 0; kk < 2; kk++) {
            bf16x8 af[4], bfr[4];
            const int ko = kk * 32 + (lane >> 4) * 8;
#pragma unroll
            for (int m = 0; m < 4; m++)
                af[m] = *reinterpret_cast<const bf16x8*>(&As[(wr * 64 + m * 16 + (lane & 15)) * BK + ko]);
#pragma unroll
            for (int n = 0; n < 4; n++)
                bfr[n] = *reinterpret_cast<const bf16x8*>(&Bs[(wc * 64 + n * 16 + (lane & 15)) * BK + ko]);
#pragma unroll
            for (int m = 0; m < 4; m++)
#pragma unroll
                for (int n = 0; n < 4; n++)
                    acc[m][n] = __builtin_amdgcn_mfma_f32_16x16x32_bf16(af[m], bfr[n], acc[m][n], 0, 0, 0);
        }
        __syncthreads();
    }

    // C/D layout: col = lane&15, row = (lane>>4)*4 + reg
    const int seg = col0 >> 8;                        // 0: mlp(relu,f32)  1: H_A(bf16)  2: H_As(bf16)
    unsigned short* hp = (seg == 1) ? HA : HAs;
    const int rb = row0 + wr * 64 + ((lane >> 4) << 2);
    const int cb = col0 + wc * 64 + (lane & 15) - seg * 256;
#pragma unroll
    for (int m = 0; m < 4; m++)
#pragma unroll
        for (int n = 0; n < 4; n++)
#pragma unroll
            for (int j = 0; j < 4; j++) {
                int r = rb + m * 16 + j;
                if (r < N_NODES) {
                    float v = acc[m][n][j];
                    int c = cb + n * 16;
                    if (seg == 0) Omlp[(size_t)r * FOUT + c] = fmaxf(v, 0.f);
                    else          hp[(size_t)r * FOUT + c] = f2bf(v);
                }
            }
}

// ---------------- binned CSR build (round-5 verified version) ----------------
// Pass 0: 391-bucket histogram per graph, LDS-aggregated
__global__ __launch_bounds__(256) void hist_kernel(const int* __restrict__ rowA, int* __restrict__ bcntA,
                                                   const int* __restrict__ rowS, int* __restrict__ bcntS) {
    __shared__ int h[2 * NB];
    const int t = threadIdx.x;
    for (int j = t; j < 2 * NB; j += 256) h[j] = 0;
    __syncthreads();
    int i = blockIdx.x * blockDim.x + t;
    const int stride = gridDim.x * blockDim.x;
    for (; i < E_EDGES; i += stride) {
        atomicAdd(&h[rowA[i] >> 7], 1);
        atomicAdd(&h[NB + (rowS[i] >> 7)], 1);
    }
    __syncthreads();
    for (int j = t; j < 2 * NB; j += 256) {
        int v = h[j];
        if (v) {
            if (j < NB) atomicAdd(&bcntA[j * CSTRIDE], v);
            else        atomicAdd(&bcntS[(j - NB) * CSTRIDE], v);
        }
    }
}

// single block, 512 threads: exclusive scan of bucket counts -> bstart (NB+1) and bcur (padded)
__global__ __launch_bounds__(512) void scan_kernel(const int* __restrict__ bcntA, int* __restrict__ bstartA,
                                                   int* __restrict__ bcurA,
                                                   const int* __restrict__ bcntS, int* __restrict__ bstartS,
                                                   int* __restrict__ bcurS) {
    __shared__ int wsum[8];
    const int t = threadIdx.x, lane = t & 63, w = t >> 6;
    for (int g = 0; g < 2; g++) {
        const int* bcnt = g ? bcntS : bcntA;
        int* bstart = g ? bstartS : bstartA;
        int* bcur = g ? bcurS : bcurA;
        int v = (t < NB) ? bcnt[t * CSTRIDE] : 0;
        int x = v;
#pragma unroll
        for (int off = 1; off < 64; off <<= 1) { int y = __shfl_up(x, off); if (lane >= off) x += y; }
        if (lane == 63) wsum[w] = x;
        __syncthreads();
        int woff = 0;
        for (int i = 0; i < w; i++) woff += wsum[i];
        int ex = woff + x - v;
        if (t < NB) { bstart[t] = ex; bcur[t * CSTRIDE] = ex; }
        if (t == 0) bstart[NB] = E_EDGES;
        __syncthreads();
    }
}

// Pass 1: chunk-per-block scatter into bucket regions (block-local runs -> L2 write-combine)
// ed1 payload: x = (row_low7 << 16) | col   (row_low7 = row & 127, col < 65536), y = val bits
__global__ __launch_bounds__(256) void pass1_kernel(
    const int* __restrict__ rowA, const int* __restrict__ colA, const float* __restrict__ valA,
    int* __restrict__ bcurA, int2* __restrict__ ed1A,
    const int* __restrict__ rowS, const int* __restrict__ colS, const float* __restrict__ valS,
    int* __restrict__ bcurS, int2* __restrict__ ed1S) {
    __shared__ int lcnt[NB];
    __shared__ int gcur[NB];
    const int t = threadIdx.x;
    const int base = blockIdx.x * CH;
    const int n = min(CH, E_EDGES - base);
    for (int g = 0; g < 2; g++) {
        const int* row = g ? rowS : rowA;
        const int* col = g ? colS : colA;
        const float* val = g ? valS : valA;
        int* bcur = g ? bcurS : bcurA;
        int2* ed1 = g ? ed1S : ed1A;
        for (int j = t; j < NB; j += 256) lcnt[j] = 0;
        __syncthreads();
        for (int j = t; j < n; j += 256) atomicAdd(&lcnt[row[base + j] >> 7], 1);
        __syncthreads();
        for (int j = t; j < NB; j += 256) {
            int c = lcnt[j];
            gcur[j] = c ? atomicAdd(&bcur[j * CSTRIDE], c) : 0;
        }
        __syncthreads();
        for (int j = t; j < n; j += 256) {
            int r = row[base + j];
            int b = r >> 7;
            int pos = atomicAdd(&gcur[b], 1);
            ed1[pos] = make_int2(((r & 127) << 16) | col[base + j], __float_as_int(val[base + j]));
        }
        __syncthreads();
    }
}

// Pass 2: one block per (graph,bucket): counting sort by key = (group-of-16, col-chunk).
// Emits group boundaries gstart[row>>4]; ed2 payload x = (row&15)<<16 | col, y = val bits.
// Within a group the edges come out chunk-ascending -> phase-coherent sweep in spmm_lds.
__global__ __launch_bounds__(256) void pass2_kernel(
    const int* __restrict__ bstartA, const int2* __restrict__ ed1A, int2* __restrict__ ed2A, int* __restrict__ gstartA,
    const int* __restrict__ bstartS, const int2* __restrict__ ed1S, int2* __restrict__ ed2S, int* __restrict__ gstartS) {
    const int g = (blockIdx.x >= NB) ? 1 : 0;
    const int b = blockIdx.x - g * NB;
    const int* bstart = g ? bstartS : bstartA;
    const int2* ed1 = g ? ed1S : ed1A;
    int2* ed2 = g ? ed2S : ed2A;
    int* gstart = g ? gstartS : gstartA;
    const int s = bstart[b], e = bstart[b + 1];
    const int t = threadIdx.x, lane = t & 63, w = t >> 6;
    __shared__ int cnt[256];
    __shared__ int exc[256];
    __shared__ int lcur[256];
    __shared__ int wsum[4];
    cnt[t] = 0;
    __syncthreads();
    for (int j = s + t; j < e; j += 256) {
        int2 v2 = ed1[j];
        int key = ((v2.x >> 16) >> 4) * NCH + ((v2.x & 0xFFFF) >> CSH);   // 0..199
        atomicAdd(&cnt[key], 1);
    }
    __syncthreads();
    const int v = cnt[t];
    int x = v;
#pragma unroll
    for (int off = 1; off < 64; off <<= 1) { int y = __shfl_up(x, off); if (lane >= off) x += y; }
    if (lane == 63) wsum[w] = x;
    __syncthreads();
    int woff = 0;
    for (int i = 0; i < w; i++) woff += wsum[i];
    const int ex = woff + x - v;
    exc[t] = ex;
    lcur[t] = s + ex;
    __syncthreads();
    if (t < 8) gstart[b * 8 + t] = s + exc[t * NCH];
    if (b == NB - 1 && t == 0) gstart[NB * 8] = E_EDGES;
    for (int j = s + t; j < e; j += 256) {
        int2 v2 = ed1[j];
        int key = ((v2.x >> 16) >> 4) * NCH + ((v2.x & 0xFFFF) >> CSH);
        int pos = atomicAdd(&lcur[key], 1);
        ed2[pos] = make_int2((((v2.x >> 16) & 15) << 16) | (v2.x & 0xFFFF), v2.y);
    }
}

// ---------------- SpMM + relu: wave = 16-row group, LDS accumulators, chunk-coherent sweep ----
// One graph per dispatch. Wave-private 16 KB LDS acc region -> dynamic row indexing without
// VGPR-indexing spill (round-5 failure mode). LDS ops are in-order per wave -> RAW safe.
__global__ __launch_bounds__(256) void spmm_lds_kernel(
    const int* __restrict__ gstart, const int2* __restrict__ ed,
    const unsigned short* __restrict__ H, unsigned short* __restrict__ O) {
    __shared__ __align__(16) float acc[4][16][256];   // 64 KB, wave-private slices
    const int wave = threadIdx.x >> 6, lane = threadIdx.x & 63;
    const int gw = blockIdx.x * 4 + wave;             // group index = row>>4
    float (* __restrict__ a)[256] = acc[wave];
#pragma unroll
    for (int r = 0; r < 16; r++)
        *reinterpret_cast<float4*>(&a[r][lane * 4]) = make_float4(0.f, 0.f, 0.f, 0.f);
    const int s = gstart[gw], e = gstart[gw + 1];
#pragma unroll 2
    for (int j = s; j < e; ++j) {
        const int2 ev = ed[j];                        // wave-uniform broadcast load
        const float val = __int_as_float(ev.y);
        const int col = ev.x & 0xFFFF;
        const int rl = ev.x >> 16;                    // 0..15
        const uint2 hv = *reinterpret_cast<const uint2*>(H + (((size_t)col) << 8) + lane * 4);
        float4 av = *reinterpret_cast<float4*>(&a[rl][lane * 4]);
        av.x += val * __uint_as_float(hv.x << 16);
        av.y += val * __uint_as_float(hv.x & 0xFFFF0000u);
        av.z += val * __uint_as_float(hv.y << 16);
        av.w += val * __uint_as_float(hv.y & 0xFFFF0000u);
        *reinterpret_cast<float4*>(&a[rl][lane * 4]) = av;
    }
    const int r0 = gw * 16;
#pragma unroll
    for (int i = 0; i < 16; i++) {
        const int r = r0 + i;
        if (r < N_NODES) {
            float4 av = *reinterpret_cast<float4*>(&a[i][lane * 4]);
            ushort4 o;
            o.x = f2bf(fmaxf(av.x, 0.f));
            o.y = f2bf(fmaxf(av.y, 0.f));
            o.z = f2bf(fmaxf(av.z, 0.f));
            o.w = f2bf(fmaxf(av.w, 0.f));
            *reinterpret_cast<ushort4*>(O + (((size_t)r) << 8) + lane * 4) = o;
        }
    }
}

// ---------------- epilogue ----------------
__global__ void colsum_kernel(const float* __restrict__ Om, const unsigned short* __restrict__ Oa,
                              const unsigned short* __restrict__ Oas, float* __restrict__ colsum) {
    const int t = threadIdx.x;
    float acc = 0.f;
    for (int r = blockIdx.x; r < N_NODES; r += gridDim.x) {
        size_t o = (size_t)r * FOUT + t;
        acc += Om[o] + bf2f(Oa[o]) + bf2f(Oas[o]);
    }
    atomicAdd(&colsum[t], acc);
}

__global__ void kvec_kernel(const float* __restrict__ colsum, const float* __restrict__ attk,
                            float* __restrict__ Kv) {
    __shared__ float mean_s[FOUT];
    const int t = threadIdx.x;
    mean_s[t] = colsum[t] * (1.0f / (float)N_NODES);
    __syncthreads();
    float acc = 0.f;
    for (int i = 0; i < FOUT; i++) acc += mean_s[i] * attk[(size_t)i * FOUT + t];
    Kv[t] = acc;
}

__global__ __launch_bounds__(256) void final_kernel(float* __restrict__ OmOut, const unsigned short* __restrict__ Oa,
                                                    const unsigned short* __restrict__ Oas, const float* __restrict__ Kv,
                                                    const float* __restrict__ attv) {
    const int r = blockIdx.x, t = threadIdx.x, lane = t & 63, w = t >> 6;
    __shared__ float red[4][3];
    __shared__ float alpha[3];
    const size_t o = (size_t)r * FOUT + t;
    const float om = OmOut[o], oa = bf2f(Oa[o]), oas = bf2f(Oas[o]);
    const float kv = Kv[t];
    float p0 = om * kv, p1 = oa * kv, p2 = oas * kv;
#pragma unroll
    for (int off = 32; off; off >>= 1) {
        p0 += __shfl_down(p0, off);
        p1 += __shfl_down(p1, off);
        p2 += __shfl_down(p2, off);
    }
    if (lane == 0) { red[w][0] = p0; red[w][1] = p1; red[w][2] = p2; }
    __syncthreads();
    if (t == 0) {
        float l0 = red[0][0] + red[1][0] + red[2][0] + red[3][0];
        float l1 = red[0][1] + red[1][1] + red[2][1] + red[3][1];
        float l2 = red[0][2] + red[1][2] + red[2][2] + red[3][2];
        float s0 = 1.f / (1.f + __expf(-l0));
        float s1 = 1.f / (1.f + __expf(-l1));
        float s2 = 1.f / (1.f + __expf(-l2));
        float q0 = (s0 * attv[0] + s1 * attv[3] + s2 * attv[6]) * (1.f / TAO_F);
        float q1 = (s0 * attv[1] + s1 * attv[4] + s2 * attv[7]) * (1.f / TAO_F);
        float q2 = (s0 * attv[2] + s1 * attv[5] + s2 * attv[8]) * (1.f / TAO_F);
        float mx = fmaxf(q0, fmaxf(q1, q2));
        float e0 = __expf(q0 - mx), e1 = __expf(q1 - mx), e2 = __expf(q2 - mx);
        float inv = 1.f / (e0 + e1 + e2);
        alpha[0] = e0 * inv; alpha[1] = e1 * inv; alpha[2] = e2 * inv;
    }
    __syncthreads();
    OmOut[o] = alpha[0] * om + alpha[1] * oa + alpha[2] * oas;
}

// ---------------- launch ----------------
extern "C" void kernel_launch(void* const* d_in, const int* in_sizes, int n_in,
                              void* d_out, int out_size, void* d_ws, size_t ws_size,
                              hipStream_t stream) {
    (void)in_sizes; (void)n_in; (void)out_size; (void)ws_size;
    const float* X        = (const float*)d_in[0];
    const int*   adj_row  = (const int*)d_in[1];
    const int*   adj_col  = (const int*)d_in[2];
    const float* adj_val  = (const float*)d_in[3];
    const int*   sadj_row = (const int*)d_in[4];
    const int*   sadj_col = (const int*)d_in[5];
    const float* sadj_val = (const float*)d_in[6];
    const float* W_mlp    = (const float*)d_in[7];
    const float* W_A      = (const float*)d_in[8];
    const float* W_As     = (const float*)d_in[9];
    const float* attk     = (const float*)d_in[10];
    const float* attv     = (const float*)d_in[11];
    float* out = (float*)d_out;

    char* p = (char*)d_ws;
    auto alloc = [&](size_t bytes) -> char* {
        char* q = p; p += (bytes + 255) & ~(size_t)255; return q;
    };
    unsigned short* Xb   = (unsigned short*)alloc((size_t)M_PAD * FIN * 2);
    unsigned short* Wt   = (unsigned short*)alloc((size_t)NCOMB * FIN * 2);
    unsigned short* H_A  = (unsigned short*)alloc((size_t)N_NODES * FOUT * 2);
    unsigned short* H_As = (unsigned short*)alloc((size_t)N_NODES * FOUT * 2);
    unsigned short* O_A  = (unsigned short*)alloc((size_t)N_NODES * FOUT * 2);
    unsigned short* O_As = (unsigned short*)alloc((size_t)N_NODES * FOUT * 2);
    int2*  ed1A  = (int2*)alloc((size_t)E_EDGES * 8);
    int2*  ed1S  = (int2*)alloc((size_t)E_EDGES * 8);
    int2*  ed2A  = (int2*)alloc((size_t)E_EDGES * 8);
    int2*  ed2S  = (int2*)alloc((size_t)E_EDGES * 8);
    int*   bcntA = (int*)alloc((size_t)NB * CSTRIDE * 4);
    int*   bcntS = (int*)alloc((size_t)NB * CSTRIDE * 4);
    int*   bcurA = (int*)alloc((size_t)NB * CSTRIDE * 4);
    int*   bcurS = (int*)alloc((size_t)NB * CSTRIDE * 4);
    int*   bstartA = (int*)alloc((size_t)(NB + 1) * 4);
    int*   bstartS = (int*)alloc((size_t)(NB + 1) * 4);
    int*   gstartA = (int*)alloc((size_t)(NGRP + 1) * 4);
    int*   gstartS = (int*)alloc((size_t)(NGRP + 1) * 4);
    float* colsum = (float*)alloc(FOUT * 4);
    float* Kv     = (float*)alloc(FOUT * 4);

    hipMemsetAsync(bcntA, 0, (size_t)NB * CSTRIDE * 4, stream);
    hipMemsetAsync(bcntS, 0, (size_t)NB * CSTRIDE * 4, stream);
    hipMemsetAsync(colsum, 0, FOUT * 4, stream);

    {
        long long total = (long long)M_PAD * FIN / 4;
        int blocks = (int)((total + 255) / 256);
        convert_x_kernel<<<blocks, 256, 0, stream>>>(X, Xb);
    }
    convert_w_kernel<<<(NCOMB * FIN + 255) / 256, 256, 0, stream>>>(W_mlp, W_A, W_As, Wt);

    // CSR build via 391-bucket two-level sort; pass2 groups rows by 16 with chunk-major edges
    hist_kernel<<<512, 256, 0, stream>>>(adj_row, bcntA, sadj_row, bcntS);
    scan_kernel<<<1, 512, 0, stream>>>(bcntA, bstartA, bcurA, bcntS, bstartS, bcurS);
    pass1_kernel<<<(E_EDGES + CH - 1) / CH, 256, 0, stream>>>(
        adj_row, adj_col, adj_val, bcurA, ed1A,
        sadj_row, sadj_col, sadj_val, bcurS, ed1S);
    pass2_kernel<<<2 * NB, 256, 0, stream>>>(bstartA, ed1A, ed2A, gstartA,
                                             bstartS, ed1S, ed2S, gstartS);

    // 1D grid with XCD-chunked swizzle
    gemm_kernel<<<GEMM_WGS, 256, 0, stream>>>(Xb, Wt, out, H_A, H_As);

    // one graph per dispatch: smaller instantaneous H working set + coherent chunk sweep
    spmm_lds_kernel<<<NGRP / 4, 256, 0, stream>>>(gstartA, ed2A, H_A, O_A);
    spmm_lds_kernel<<<NGRP / 4, 256, 0, stream>>>(gstartS, ed2S, H_As, O_As);

    colsum_kernel<<<512, 256, 0, stream>>>(out, O_A, O_As, colsum);
    kvec_kernel<<<1, 256, 0, stream>>>(colsum, attk, Kv);
    final_kernel<<<N_NODES, 256, 0, stream>>>(out, O_A, O_As, Kv, attv);
}

// Round 8
// 538.770 us; speedup vs baseline: 1.8535x; 1.8535x over previous
//
#include <hip/hip_runtime.h>
#include <hip/hip_bf16.h>

// Problem constants (from reference)
#define N_NODES 50000
#define E_EDGES 1600000
#define FIN 512
#define FOUT 256
#define NCOMB 768      // 3 * FOUT, fused GEMM N
#define TAO_F 3.0f
#define M_PAD 50048    // 391 * 128
#define N_RPAD 50048   // padded row count for 8-row spmm waves
#define NB 196         // buckets = ceil(N / 256), bucket = row >> 8
#define CSTRIDE 16     // global counter padding (one per 64B line)
#define CH 4096        // edges per block in pass 1
#define NCH 13         // col chunks in pass 2: col>>12, col<50000 -> 0..12
#define RPW 8          // rows per spmm wave
#define WPG 6256       // waves per graph = N_RPAD / RPW

#define GEMM_WGS 2346  // 391 * 6 workgroups, flattened
#define GEMM_Q  (GEMM_WGS / 8)   // 293
#define GEMM_R  (GEMM_WGS % 8)   // 2

typedef __bf16 bf16x8 __attribute__((ext_vector_type(8)));
typedef float  f32x4  __attribute__((ext_vector_type(4)));

static __device__ __forceinline__ unsigned short f2bf(float f) {
    unsigned int u = __float_as_uint(f);
    u += 0x7FFFu + ((u >> 16) & 1u);   // round-to-nearest-even
    return (unsigned short)(u >> 16);
}
static __device__ __forceinline__ float bf2f(unsigned short h) {
    return __uint_as_float(((unsigned int)h) << 16);
}

// ---------------- conversion kernels ----------------
__global__ void convert_x_kernel(const float* __restrict__ X, unsigned short* __restrict__ Xb) {
    long long i = ((long long)blockIdx.x * blockDim.x + threadIdx.x) * 4;
    const long long total = (long long)M_PAD * FIN;
    if (i >= total) return;
    const long long valid = (long long)N_NODES * FIN;   // divisible by 4
    ushort4 o;
    if (i < valid) {
        const float4 v = *reinterpret_cast<const float4*>(X + i);
        o.x = f2bf(v.x); o.y = f2bf(v.y); o.z = f2bf(v.z); o.w = f2bf(v.w);
    } else {
        o.x = o.y = o.z = o.w = 0;
    }
    *reinterpret_cast<ushort4*>(Xb + i) = o;
}

// three W (FIN x FOUT f32) -> combined Wt (NCOMB x FIN bf16), row w*256+n = col n of W_w
__global__ void convert_w_kernel(const float* __restrict__ Wm, const float* __restrict__ Wa,
                                 const float* __restrict__ Was, unsigned short* __restrict__ Wt) {
    int i = blockIdx.x * blockDim.x + threadIdx.x;
    if (i >= NCOMB * FIN) return;
    int row = i / FIN, k = i % FIN;
    int w = row >> 8, n = row & 255;
    const float* W = (w == 0) ? Wm : (w == 1) ? Wa : Was;
    Wt[i] = f2bf(W[(size_t)k * FOUT + n]);
}

// ---------------- fused bf16 MFMA GEMM: [Hm|H_A|H_As] = A(M_PAD x FIN) * Wt(NCOMB x FIN)^T ----
// All outputs bf16; seg 0 applies relu AND accumulates column partial sums into colsum8.
#define BM 128
#define BN 128
#define BK 64

__global__ __launch_bounds__(256) void gemm_kernel(const unsigned short* __restrict__ A,
                                                   const unsigned short* __restrict__ Bt,
                                                   unsigned short* __restrict__ Hm,
                                                   unsigned short* __restrict__ HA,
                                                   unsigned short* __restrict__ HAs,
                                                   float* __restrict__ colsum8) {
    __shared__ unsigned short As[BM * BK];   // [128][64] linear (global_load_lds dest)
    __shared__ unsigned short Bs[BN * BK];
    __shared__ float csm[128];
    const int b = blockIdx.x;
    const int xcd = b & 7, ii = b >> 3;
    const int work = (xcd < GEMM_R ? xcd * (GEMM_Q + 1)
                                   : GEMM_R * (GEMM_Q + 1) + (xcd - GEMM_R) * GEMM_Q) + ii;
    const int py = work / 6, px = work - py * 6;
    const int row0 = py * BM, col0 = px * BN;
    const int tid = threadIdx.x;
    const int lane = tid & 63, wave = tid >> 6;
    const int wr = wave >> 1, wc = wave & 1;          // 2x2 waves -> 64x64 each
    if (tid < 128) csm[tid] = 0.f;
    const int st_row = tid >> 3;
    const int st_col = (tid & 7) * 8;
    const int lds_off = wave * 512;
    const unsigned short* Ag = A + (size_t)(row0 + st_row) * FIN + st_col;
    const unsigned short* Bg = Bt + (size_t)(col0 + st_row) * FIN + st_col;
    f32x4 acc[4][4] = {};

    for (int k0 = 0; k0 < FIN; k0 += BK) {
#pragma unroll
        for (int i = 0; i < 4; i++) {
            __builtin_amdgcn_global_load_lds(
                (const __attribute__((address_space(1))) unsigned int*)(Ag + (size_t)i * 32 * FIN + k0),
                (__attribute__((address_space(3))) unsigned int*)&As[i * 2048 + lds_off], 16, 0, 0);
            __builtin_amdgcn_global_load_lds(
                (const __attribute__((address_space(1))) unsigned int*)(Bg + (size_t)i * 32 * FIN + k0),
                (__attribute__((address_space(3))) unsigned int*)&Bs[i * 2048 + lds_off], 16, 0, 0);
        }
        __syncthreads();
#pragma unroll
        for (int kk = 0; kk < 2; kk++) {
            bf16x8 af[4], bfr[4];
            const int ko = kk * 32 + (lane >> 4) * 8;
#pragma unroll
            for (int m = 0; m < 4; m++)
                af[m] = *reinterpret_cast<const bf16x8*>(&As[(wr * 64 + m * 16 + (lane & 15)) * BK + ko]);
#pragma unroll
            for (int n = 0; n < 4; n++)
                bfr[n] = *reinterpret_cast<const bf16x8*>(&Bs[(wc * 64 + n * 16 + (lane & 15)) * BK + ko]);
#pragma unroll
            for (int m = 0; m < 4; m++)
#pragma unroll
                for (int n = 0; n < 4; n++)
                    acc[m][n] = __builtin_amdgcn_mfma_f32_16x16x32_bf16(af[m], bfr[n], acc[m][n], 0, 0, 0);
        }
        __syncthreads();
    }

    // C/D layout: col = lane&15, row = (lane>>4)*4 + reg
    const int seg = col0 >> 8;                        // 0: mlp(relu,+colsum)  1: H_A  2: H_As
    unsigned short* hp = (seg == 0) ? Hm : (seg == 1) ? HA : HAs;
    const int rb = row0 + wr * 64 + ((lane >> 4) << 2);
    const int cb_loc = wc * 64 + (lane & 15);         // 0..127 block-local col base
    const int cbase = col0 - seg * 256 + cb_loc;
    float part[4] = {0.f, 0.f, 0.f, 0.f};
#pragma unroll
    for (int m = 0; m < 4; m++)
#pragma unroll
        for (int n = 0; n < 4; n++)
#pragma unroll
            for (int j = 0; j < 4; j++) {
                int r = rb + m * 16 + j;
                if (r < N_NODES) {
                    float v = acc[m][n][j];
                    if (seg == 0) { v = fmaxf(v, 0.f); part[n] += v; }
                    hp[(size_t)r * FOUT + cbase + n * 16] = f2bf(v);
                }
            }
    if (seg == 0) {
#pragma unroll
        for (int n = 0; n < 4; n++) atomicAdd(&csm[cb_loc + n * 16], part[n]);
        __syncthreads();
        if (tid < 128) atomicAdd(&colsum8[((b & 7) << 8) + col0 + tid], csm[tid]);
    }
}

// ---------------- binned CSR build ----------------
// Pass 0: 196-bucket histogram per graph, LDS-aggregated
__global__ __launch_bounds__(256) void hist_kernel(const int* __restrict__ rowA, int* __restrict__ bcntA,
                                                   const int* __restrict__ rowS, int* __restrict__ bcntS) {
    __shared__ int h[2 * NB];
    const int t = threadIdx.x;
    for (int j = t; j < 2 * NB; j += 256) h[j] = 0;
    __syncthreads();
    int i = blockIdx.x * blockDim.x + t;
    const int stride = gridDim.x * blockDim.x;
    for (; i < E_EDGES; i += stride) {
        atomicAdd(&h[rowA[i] >> 8], 1);
        atomicAdd(&h[NB + (rowS[i] >> 8)], 1);
    }
    __syncthreads();
    for (int j = t; j < 2 * NB; j += 256) {
        int v = h[j];
        if (v) {
            if (j < NB) atomicAdd(&bcntA[j * CSTRIDE], v);
            else        atomicAdd(&bcntS[(j - NB) * CSTRIDE], v);
        }
    }
}

// single block: exclusive scan of bucket counts -> bstart (NB+1) and bcur (padded)
__global__ __launch_bounds__(256) void scan196_kernel(const int* __restrict__ bcntA, int* __restrict__ bstartA,
                                                      int* __restrict__ bcurA,
                                                      const int* __restrict__ bcntS, int* __restrict__ bstartS,
                                                      int* __restrict__ bcurS) {
    __shared__ int wsum[4];
    const int t = threadIdx.x, lane = t & 63, w = t >> 6;
    for (int g = 0; g < 2; g++) {
        const int* bcnt = g ? bcntS : bcntA;
        int* bstart = g ? bstartS : bstartA;
        int* bcur = g ? bcurS : bcurA;
        int v = (t < NB) ? bcnt[t * CSTRIDE] : 0;
        int x = v;
#pragma unroll
        for (int off = 1; off < 64; off <<= 1) { int y = __shfl_up(x, off); if (lane >= off) x += y; }
        if (lane == 63) wsum[w] = x;
        __syncthreads();
        int woff = 0;
        for (int i = 0; i < w; i++) woff += wsum[i];
        int ex = woff + x - v;
        if (t < NB) { bstart[t] = ex; bcur[t * CSTRIDE] = ex; }
        if (t == 0) bstart[NB] = E_EDGES;
        __syncthreads();
    }
}

// Pass 1: chunk-per-block scatter into bucket regions (block-local runs -> L2 write-combine)
// ed1 payload: x = (row_low << 16) | col   (row_low = row & 255, col < 65536), y = val bits
__global__ __launch_bounds__(256) void pass1_kernel(
    const int* __restrict__ rowA, const int* __restrict__ colA, const float* __restrict__ valA,
    int* __restrict__ bcurA, int2* __restrict__ ed1A,
    const int* __restrict__ rowS, const int* __restrict__ colS, const float* __restrict__ valS,
    int* __restrict__ bcurS, int2* __restrict__ ed1S) {
    __shared__ int lcnt[NB];
    __shared__ int gcur[NB];
    const int t = threadIdx.x;
    const int base = blockIdx.x * CH;
    const int n = min(CH, E_EDGES - base);
    for (int g = 0; g < 2; g++) {
        const int* row = g ? rowS : rowA;
        const int* col = g ? colS : colA;
        const float* val = g ? valS : valA;
        int* bcur = g ? bcurS : bcurA;
        int2* ed1 = g ? ed1S : ed1A;
        for (int j = t; j < NB; j += 256) lcnt[j] = 0;
        __syncthreads();
        for (int j = t; j < n; j += 256) atomicAdd(&lcnt[row[base + j] >> 8], 1);
        __syncthreads();
        for (int j = t; j < NB; j += 256) {
            int c = lcnt[j];
            gcur[j] = c ? atomicAdd(&bcur[j * CSTRIDE], c) : 0;
        }
        __syncthreads();
        for (int j = t; j < n; j += 256) {
            int r = row[base + j];
            int b = r >> 8;
            int pos = atomicAdd(&gcur[b], 1);
            ed1[pos] = make_int2(((r & 255) << 16) | col[base + j], __float_as_int(val[base + j]));
        }
        __syncthreads();
    }
}

// Pass 2: one block per bucket: (row, col-chunk) counting sort -> rp + in-bucket scatter.
// rp is padded: rows [N, N_RPAD] get rp = E.
__global__ __launch_bounds__(256) void pass2_kernel(
    const int* __restrict__ bstartA, const int2* __restrict__ ed1A, int2* __restrict__ ed2A, int* __restrict__ rpA,
    const int* __restrict__ bstartS, const int2* __restrict__ ed1S, int2* __restrict__ ed2S, int* __restrict__ rpS) {
    const int g = (blockIdx.x >= NB) ? 1 : 0;
    const int b = blockIdx.x - g * NB;
    const int* bstart = g ? bstartS : bstartA;
    const int2* ed1 = g ? ed1S : ed1A;
    int2* ed2 = g ? ed2S : ed2A;
    int* rp = g ? rpS : rpA;
    const int s = bstart[b], e = bstart[b + 1];
    const int t = threadIdx.x, lane = t & 63, w = t >> 6;
    __shared__ int rcnt[256 * NCH];
    __shared__ int lcur[256 * NCH];
    __shared__ int wsum[4];
    for (int j = t; j < 256 * NCH; j += 256) rcnt[j] = 0;
    __syncthreads();
    for (int j = s + t; j < e; j += 256) {
        int2 v2 = ed1[j];
        atomicAdd(&rcnt[(v2.x >> 16) * NCH + ((v2.x & 0xFFFF) >> 12)], 1);
    }
    __syncthreads();
    int rsum = 0;
#pragma unroll
    for (int c = 0; c < NCH; c++) rsum += rcnt[t * NCH + c];
    int x = rsum;
#pragma unroll
    for (int off = 1; off < 64; off <<= 1) { int y = __shfl_up(x, off); if (lane >= off) x += y; }
    if (lane == 63) wsum[w] = x;
    __syncthreads();
    int woff = 0;
    for (int i = 0; i < w; i++) woff += wsum[i];
    const int ex = woff + x - rsum;       // exclusive row offset within bucket
    const int row = b * 256 + t;
    if (row < N_NODES) rp[row] = s + ex;
    else if (row <= N_RPAD) rp[row] = E_EDGES;
    int off2 = ex;
#pragma unroll
    for (int c = 0; c < NCH; c++) { lcur[t * NCH + c] = off2; off2 += rcnt[t * NCH + c]; }
    __syncthreads();
    for (int j = s + t; j < e; j += 256) {
        int2 v2 = ed1[j];
        int rl = v2.x >> 16, cc = (v2.x & 0xFFFF) >> 12;
        int k = atomicAdd(&lcur[rl * NCH + cc], 1);
        ed2[s + k] = make_int2(v2.x & 0xFFFF, v2.y);
    }
}

// ---------------- SpMM + relu, 8 rows per wave, both graphs; bf16 output; fused colsum ----
__global__ __launch_bounds__(256) void spmm_kernel(
    const int* __restrict__ rpA, const int2* __restrict__ edA,
    const unsigned short* __restrict__ HA, unsigned short* __restrict__ OA,
    const int* __restrict__ rpS, const int2* __restrict__ edS,
    const unsigned short* __restrict__ HS, unsigned short* __restrict__ OS,
    float* __restrict__ colsum8) {
    __shared__ float csum[256];
    const int t = threadIdx.x, wave = t >> 6, lane = t & 63;
    csum[t] = 0.f;
    __syncthreads();
    const int gwave = blockIdx.x * 4 + wave;          // 0 .. 2*WPG-1
    const int g = (gwave >= WPG) ? 1 : 0;
    const int wv = gwave - g * WPG;
    const int* rp = g ? rpS : rpA;
    const int2* ed = g ? edS : edA;
    const unsigned short* H = g ? HS : HA;
    unsigned short* O = g ? OS : OA;
    const int r0 = wv * RPW;
    float cs0 = 0.f, cs1 = 0.f, cs2 = 0.f, cs3 = 0.f;
    int s = rp[r0];
#pragma unroll
    for (int i = 0; i < RPW; i++) {
        const int r = r0 + i;
        const int e = rp[r + 1];
        float a0 = 0.f, a1 = 0.f, a2 = 0.f, a3 = 0.f;
#pragma unroll 4
        for (int j = s; j < e; ++j) {
            const int2 ev = ed[j];                   // wave-uniform broadcast load
            const float v = __int_as_float(ev.y);
            const uint2 hv = *reinterpret_cast<const uint2*>(H + (((size_t)ev.x) << 8) + lane * 4);
            a0 += v * bf2f((unsigned short)(hv.x & 0xFFFFu));
            a1 += v * bf2f((unsigned short)(hv.x >> 16));
            a2 += v * bf2f((unsigned short)(hv.y & 0xFFFFu));
            a3 += v * bf2f((unsigned short)(hv.y >> 16));
        }
        s = e;
        if (r < N_NODES) {
            a0 = fmaxf(a0, 0.f); a1 = fmaxf(a1, 0.f);
            a2 = fmaxf(a2, 0.f); a3 = fmaxf(a3, 0.f);
            cs0 += a0; cs1 += a1; cs2 += a2; cs3 += a3;
            ushort4 o;
            o.x = f2bf(a0); o.y = f2bf(a1); o.z = f2bf(a2); o.w = f2bf(a3);
            *reinterpret_cast<ushort4*>(O + (((size_t)r) << 8) + lane * 4) = o;
        }
    }
    atomicAdd(&csum[lane * 4 + 0], cs0);
    atomicAdd(&csum[lane * 4 + 1], cs1);
    atomicAdd(&csum[lane * 4 + 2], cs2);
    atomicAdd(&csum[lane * 4 + 3], cs3);
    __syncthreads();
    atomicAdd(&colsum8[((blockIdx.x & 7) << 8) + t], csum[t]);
}

// ---------------- epilogue ----------------
__global__ void kvec_kernel(const float* __restrict__ colsum8, const float* __restrict__ attk,
                            float* __restrict__ Kv) {
    __shared__ float mean_s[FOUT];
    const int t = threadIdx.x;
    float cs = 0.f;
#pragma unroll
    for (int k = 0; k < 8; k++) cs += colsum8[(k << 8) + t];
    mean_s[t] = cs * (1.0f / (float)N_NODES);
    __syncthreads();
    float acc = 0.f;
    for (int i = 0; i < FOUT; i++) acc += mean_s[i] * attk[(size_t)i * FOUT + t];
    Kv[t] = acc;
}

__global__ __launch_bounds__(256) void final_kernel(float* __restrict__ out,
                                                    const unsigned short* __restrict__ Omb,
                                                    const unsigned short* __restrict__ Oa,
                                                    const unsigned short* __restrict__ Oas,
                                                    const float* __restrict__ Kv,
                                                    const float* __restrict__ attv) {
    const int r = blockIdx.x, t = threadIdx.x, lane = t & 63, w = t >> 6;
    __shared__ float red[4][3];
    __shared__ float alpha[3];
    const size_t o = (size_t)r * FOUT + t;
    const float om = bf2f(Omb[o]), oa = bf2f(Oa[o]), oas = bf2f(Oas[o]);
    const float kv = Kv[t];
    float p0 = om * kv, p1 = oa * kv, p2 = oas * kv;
#pragma unroll
    for (int off = 32; off; off >>= 1) {
        p0 += __shfl_down(p0, off);
        p1 += __shfl_down(p1, off);
        p2 += __shfl_down(p2, off);
    }
    if (lane == 0) { red[w][0] = p0; red[w][1] = p1; red[w][2] = p2; }
    __syncthreads();
    if (t == 0) {
        float l0 = red[0][0] + red[1][0] + red[2][0] + red[3][0];
        float l1 = red[0][1] + red[1][1] + red[2][1] + red[3][1];
        float l2 = red[0][2] + red[1][2] + red[2][2] + red[3][2];
        float s0 = 1.f / (1.f + __expf(-l0));
        float s1 = 1.f / (1.f + __expf(-l1));
        float s2 = 1.f / (1.f + __expf(-l2));
        float q0 = (s0 * attv[0] + s1 * attv[3] + s2 * attv[6]) * (1.f / TAO_F);
        float q1 = (s0 * attv[1] + s1 * attv[4] + s2 * attv[7]) * (1.f / TAO_F);
        float q2 = (s0 * attv[2] + s1 * attv[5] + s2 * attv[8]) * (1.f / TAO_F);
        float mx = fmaxf(q0, fmaxf(q1, q2));
        float e0 = __expf(q0 - mx), e1 = __expf(q1 - mx), e2 = __expf(q2 - mx);
        float inv = 1.f / (e0 + e1 + e2);
        alpha[0] = e0 * inv; alpha[1] = e1 * inv; alpha[2] = e2 * inv;
    }
    __syncthreads();
    out[o] = alpha[0] * om + alpha[1] * oa + alpha[2] * oas;
}

// ---------------- launch ----------------
extern "C" void kernel_launch(void* const* d_in, const int* in_sizes, int n_in,
                              void* d_out, int out_size, void* d_ws, size_t ws_size,
                              hipStream_t stream) {
    (void)in_sizes; (void)n_in; (void)out_size; (void)ws_size;
    const float* X        = (const float*)d_in[0];
    const int*   adj_row  = (const int*)d_in[1];
    const int*   adj_col  = (const int*)d_in[2];
    const float* adj_val  = (const float*)d_in[3];
    const int*   sadj_row = (const int*)d_in[4];
    const int*   sadj_col = (const int*)d_in[5];
    const float* sadj_val = (const float*)d_in[6];
    const float* W_mlp    = (const float*)d_in[7];
    const float* W_A      = (const float*)d_in[8];
    const float* W_As     = (const float*)d_in[9];
    const float* attk     = (const float*)d_in[10];
    const float* attv     = (const float*)d_in[11];
    float* out = (float*)d_out;

    char* p = (char*)d_ws;
    auto alloc = [&](size_t bytes) -> char* {
        char* q = p; p += (bytes + 255) & ~(size_t)255; return q;
    };
    unsigned short* Xb   = (unsigned short*)alloc((size_t)M_PAD * FIN * 2);
    unsigned short* Wt   = (unsigned short*)alloc((size_t)NCOMB * FIN * 2);
    unsigned short* H_M  = (unsigned short*)alloc((size_t)N_NODES * FOUT * 2);
    unsigned short* H_A  = (unsigned short*)alloc((size_t)N_NODES * FOUT * 2);
    unsigned short* H_As = (unsigned short*)alloc((size_t)N_NODES * FOUT * 2);
    unsigned short* O_A  = (unsigned short*)alloc((size_t)N_NODES * FOUT * 2);
    unsigned short* O_As = (unsigned short*)alloc((size_t)N_NODES * FOUT * 2);
    int2*  ed1A  = (int2*)alloc((size_t)E_EDGES * 8);
    int2*  ed1S  = (int2*)alloc((size_t)E_EDGES * 8);
    int2*  ed2A  = (int2*)alloc((size_t)E_EDGES * 8);
    int2*  ed2S  = (int2*)alloc((size_t)E_EDGES * 8);
    int*   bcntA = (int*)alloc((size_t)NB * CSTRIDE * 4);
    int*   bcntS = (int*)alloc((size_t)NB * CSTRIDE * 4);
    int*   bcurA = (int*)alloc((size_t)NB * CSTRIDE * 4);
    int*   bcurS = (int*)alloc((size_t)NB * CSTRIDE * 4);
    int*   bstartA = (int*)alloc((size_t)(NB + 1) * 4);
    int*   bstartS = (int*)alloc((size_t)(NB + 1) * 4);
    int*   rpA   = (int*)alloc((size_t)(N_RPAD + 1) * 4);
    int*   rpS   = (int*)alloc((size_t)(N_RPAD + 1) * 4);
    float* colsum8 = (float*)alloc(8 * FOUT * 4);
    float* Kv      = (float*)alloc(FOUT * 4);

    hipMemsetAsync(bcntA, 0, (size_t)NB * CSTRIDE * 4, stream);
    hipMemsetAsync(bcntS, 0, (size_t)NB * CSTRIDE * 4, stream);
    hipMemsetAsync(colsum8, 0, 8 * FOUT * 4, stream);

    {
        long long total = (long long)M_PAD * FIN / 4;
        int blocks = (int)((total + 255) / 256);
        convert_x_kernel<<<blocks, 256, 0, stream>>>(X, Xb);
    }
    convert_w_kernel<<<(NCOMB * FIN + 255) / 256, 256, 0, stream>>>(W_mlp, W_A, W_As, Wt);

    // CSR build via 196-bucket two-level sort (pass2 col-chunk-orders within row, pads rp)
    hist_kernel<<<512, 256, 0, stream>>>(adj_row, bcntA, sadj_row, bcntS);
    scan196_kernel<<<1, 256, 0, stream>>>(bcntA, bstartA, bcurA, bcntS, bstartS, bcurS);
    pass1_kernel<<<(E_EDGES + CH - 1) / CH, 256, 0, stream>>>(
        adj_row, adj_col, adj_val, bcurA, ed1A,
        sadj_row, sadj_col, sadj_val, bcurS, ed1S);
    pass2_kernel<<<2 * NB, 256, 0, stream>>>(bstartA, ed1A, ed2A, rpA,
                                             bstartS, ed1S, ed2S, rpS);

    // 1D grid with XCD-chunked swizzle; bf16 outputs; seg0 fuses relu + colsum
    gemm_kernel<<<GEMM_WGS, 256, 0, stream>>>(Xb, Wt, H_M, H_A, H_As, colsum8);

    // 8 rows/wave; fused colsum; both graphs in one dispatch
    spmm_kernel<<<(2 * WPG) / 4, 256, 0, stream>>>(rpA, ed2A, H_A, O_A,
                                                   rpS, ed2S, H_As, O_As, colsum8);

    kvec_kernel<<<1, 256, 0, stream>>>(colsum8, attk, Kv);
    final_kernel<<<N_NODES, 256, 0, stream>>>(out, H_M, O_A, O_As, Kv, attv);
}